// Round 3
// baseline (2696.881 us; speedup 1.0000x reference)
//
#include <hip/hip_runtime.h>

#define CC 64
#define HH 256
#define WW 256
#define HW (HH * WW)

typedef float v2f __attribute__((ext_vector_type(2)));

// Wcomb[((i*64 + c)*9 + t)*64 + o] = sum_c2 Wfuse[o, i*64+c2] * Wd[i, c2, c, t]
__global__ void wcomb_kernel(const float* __restrict__ Wd,
                             const float* __restrict__ Wfuse,
                             float* __restrict__ Wcomb) {
    int idx = blockIdx.x * blockDim.x + threadIdx.x;
    if (idx >= 3 * 64 * 9 * 64) return;
    int o = idx & 63;
    int ct = idx >> 6;        // ((i*64 + c)*9 + t)
    int t = ct % 9;
    int c = (ct / 9) & 63;
    int i = ct / 9 / 64;
    const float* wf = Wfuse + o * 192 + i * 64;                    // c2 stride 1
    const float* wd = Wd + ((size_t)(i * 64) * 64 + c) * 9 + t;   // c2 stride 576
    float s = 0.f;
    for (int c2 = 0; c2 < 64; ++c2)
        s = fmaf(wf[c2], wd[(size_t)c2 * 576], s);
    Wcomb[idx] = s;
}

// Block = 4 waves cooperating on one 64-pixel tile. K-split: wave wv handles
// input channels [wv*16, wv*16+16) for phase 1 (offset conv) AND phase 2
// (gather + matvec). Partials combined in LDS. 2048 blocks -> 4096 waves
// (2x occupancy vs one-wave-per-tile). XCD swizzle: blockIdx&7 -> 64-row band.
__launch_bounds__(256, 4)
__global__ void mspadc_main(const float* __restrict__ x,
                            const float* __restrict__ Woff,
                            const float* __restrict__ boff,
                            const float* __restrict__ Wcomb,
                            float* __restrict__ out) {
    __shared__ float offL[27 * 64 * 2];   // [n][pixel][dy,dx]  13.8 KB
    __shared__ float accL[64 * 64];       // [o][pixel]         16.4 KB

    const int tid = threadIdx.x;
    const int lane = tid & 63;
    const int wv = tid >> 6;

    const int xcd = blockIdx.x & 7;
    const int idx = blockIdx.x >> 3;          // 0..255 per XCD
    const int row = xcd * 64 + (idx >> 2);    // 0..511
    const int wseg = idx & 3;
    const int b = row >> 8;
    const int h = row & 255;
    const int w = (wseg << 6) + lane;

    // ---- init LDS: offL <- boff broadcast, accL <- 0 ----
    for (int f = tid; f < 27 * 64 * 2; f += 256) {
        const int n = f >> 7;
        const int comp = f & 1;
        offL[f] = boff[(n << 1) | comp];
    }
    for (int f = tid; f < 64 * 64; f += 256) accL[f] = 0.f;
    __syncthreads();

    const float* xb = x + (size_t)b * CC * HW;
    const int c0 = wv * 16;

    // ---- Phase 1: partial offset conv over this wave's 16 channels ----
    {
        v2f off2[27];
#pragma unroll
        for (int n = 0; n < 27; ++n) off2[n] = (v2f){0.f, 0.f};

        const float* xc = xb + (size_t)c0 * HW;
        for (int cc = 0; cc < 16; ++cc, xc += HW) {
            float xv[9];
#pragma unroll
            for (int t = 0; t < 9; ++t) {
                const int yy = h + (t / 3) - 1;
                const int xx = w + (t % 3) - 1;
                const bool v = (yy >= 0) && (yy < HH) && (xx >= 0) && (xx < WW);
                xv[t] = v ? xc[yy * WW + xx] : 0.f;
            }
            const float* wp = Woff + (c0 + cc) * 9;   // + n*576 + t
#pragma unroll
            for (int n = 0; n < 27; ++n) {
                v2f a = off2[n];
#pragma unroll
                for (int t = 0; t < 9; ++t) {
                    v2f wt = { wp[(2 * n) * 576 + t], wp[(2 * n + 1) * 576 + t] };
                    v2f xt = { xv[t], xv[t] };
                    a = __builtin_elementwise_fma(wt, xt, a);
                }
                off2[n] = a;
            }
        }
#pragma unroll
        for (int n = 0; n < 27; ++n) {
            atomicAdd(&offL[(n * 64 + lane) * 2 + 0], off2[n].x);
            atomicAdd(&offL[(n * 64 + lane) * 2 + 1], off2[n].y);
        }
    }
    __syncthreads();

    // ---- Phase 2: gather + matvec over this wave's 16 channels ----
    v2f acc2[32];
#pragma unroll
    for (int o = 0; o < 32; ++o) acc2[o] = (v2f){0.f, 0.f};

    const float fh = (float)h, fw = (float)w;

    for (int i = 0; i < 3; ++i) {
        const int d = 1 << i;   // 1,2,4
        for (int t = 0; t < 9; ++t) {
            const v2f o2 = *(const v2f*)&offL[((i * 9 + t) * 64 + lane) * 2];
            const float dy = o2.x, dx = o2.y;
            const float ys = fh + (float)((t / 3 - 1) * d) + dy;
            const float xs = fw + (float)((t % 3 - 1) * d) + dx;
            const float y0f = floorf(ys), x0f = floorf(xs);
            const float wy1 = ys - y0f, wx1 = xs - x0f;
            const float wy0 = 1.f - wy1, wx0 = 1.f - wx1;
            const float vy0 = (y0f >= 0.f && y0f <= 255.f) ? 1.f : 0.f;
            const float vy1 = (y0f >= -1.f && y0f <= 254.f) ? 1.f : 0.f;
            const float vx0 = (x0f >= 0.f && x0f <= 255.f) ? 1.f : 0.f;
            const float vx1 = (x0f >= -1.f && x0f <= 254.f) ? 1.f : 0.f;
            const float c00 = wy0 * wx0 * vy0 * vx0;
            const float c01 = wy0 * wx1 * vy0 * vx1;
            const float c10 = wy1 * wx0 * vy1 * vx0;
            const float c11 = wy1 * wx1 * vy1 * vx1;
            const int y0 = (int)fminf(fmaxf(y0f, 0.f), 255.f);
            const int y1 = (int)fminf(fmaxf(y0f + 1.f, 0.f), 255.f);
            const int x0 = (int)fminf(fmaxf(x0f, 0.f), 255.f);
            const int x1 = (int)fminf(fmaxf(x0f + 1.f, 0.f), 255.f);
            const int o00 = y0 * WW + x0;
            const int oxs = x1 - x0;          // 0 or 1
            const int oyW = (y1 - y0) * WW;   // 0 or WW

            const float* pc = xb + (size_t)c0 * HW;
            const float* wcb = Wcomb + (size_t)(((i * 64 + c0) * 9 + t)) * 64;
#pragma unroll 4
            for (int cc = 0; cc < 16; ++cc, pc += HW) {
                float sv = pc[o00] * c00;
                sv = fmaf(pc[o00 + oxs], c01, sv);
                sv = fmaf(pc[o00 + oyW], c10, sv);
                sv = fmaf(pc[o00 + oyW + oxs], c11, sv);
                const v2f sv2 = { sv, sv };
                const v2f* w2 = (const v2f*)(wcb + (size_t)cc * 9 * 64);
#pragma unroll
                for (int o = 0; o < 32; ++o)
                    acc2[o] = __builtin_elementwise_fma(w2[o], sv2, acc2[o]);
            }
        }
    }

#pragma unroll
    for (int o = 0; o < 32; ++o) {
        atomicAdd(&accL[(2 * o) * 64 + lane], acc2[o].x);
        atomicAdd(&accL[(2 * o + 1) * 64 + lane], acc2[o].y);
    }
    __syncthreads();

    // ---- writeout: thread tid -> pixel (tid&63), o-range (tid>>6)*16 ----
    {
        const int p = tid & 63;
        const int ob = (tid >> 6) << 4;
        float* op = out + ((size_t)b * 64 + ob) * HW + h * WW + (wseg << 6) + p;
#pragma unroll
        for (int j = 0; j < 16; ++j)
            op[(size_t)j * HW] = accL[(ob + j) * 64 + p];
    }
}

extern "C" void kernel_launch(void* const* d_in, const int* in_sizes, int n_in,
                              void* d_out, int out_size, void* d_ws, size_t ws_size,
                              hipStream_t stream) {
    const float* x     = (const float*)d_in[0];
    const float* Woff  = (const float*)d_in[1];
    const float* boff  = (const float*)d_in[2];
    const float* Wd    = (const float*)d_in[3];
    const float* Wfuse = (const float*)d_in[4];
    float* out = (float*)d_out;
    float* Wcomb = (float*)d_ws;   // 3*64*9*64 floats = 442,368 B

    wcomb_kernel<<<432, 256, 0, stream>>>(Wd, Wfuse, Wcomb);
    mspadc_main<<<2048, 256, 0, stream>>>(x, Woff, boff, Wcomb, out);
}

// Round 4
// 413.636 us; speedup vs baseline: 6.5199x; 6.5199x over previous
//
#include <hip/hip_runtime.h>

#define HH 256
#define WW 256
#define HW (HH * WW)

typedef float f32x4 __attribute__((ext_vector_type(4)));
typedef short bf16x8 __attribute__((ext_vector_type(8)));

__device__ __forceinline__ unsigned short f2bf(float f) {
    unsigned u = __builtin_bit_cast(unsigned, f);
    return (unsigned short)((u + 0x7FFFu + ((u >> 16) & 1u)) >> 16);
}
__device__ __forceinline__ float blo(unsigned u) { return __builtin_bit_cast(float, u << 16); }
__device__ __forceinline__ float bhi(unsigned u) { return __builtin_bit_cast(float, u & 0xFFFF0000u); }

// x[b][c][h][w] fp32 -> xT[b][h][w][c] bf16  (channel-last for 16B gathers)
__global__ void xt_kernel(const float* __restrict__ x, unsigned short* __restrict__ xT) {
    const int pix = blockIdx.x * 256 + threadIdx.x;       // 0..131071
    const float* xp = x + (size_t)(pix >> 16) * 64 * HW + (pix & 65535);
    unsigned short* op = xT + (size_t)pix * 64;
#pragma unroll
    for (int c8 = 0; c8 < 8; ++c8) {
        unsigned q[4];
#pragma unroll
        for (int j = 0; j < 4; ++j) {
            float a = xp[(size_t)(c8 * 8 + 2 * j) * HW];
            float b = xp[(size_t)(c8 * 8 + 2 * j + 1) * HW];
            q[j] = (unsigned)f2bf(a) | ((unsigned)f2bf(b) << 16);
        }
        *(uint4*)(op + c8 * 8) = make_uint4(q[0], q[1], q[2], q[3]);
    }
}

// WcombB[s][o][c] bf16, s=i*9+t:  sum_c2 Wfuse[o][i*64+c2] * Wd[i][c2][c][t]
__global__ void wcomb_kernel(const float* __restrict__ Wd,
                             const float* __restrict__ Wfuse,
                             unsigned short* __restrict__ WcombB) {
    int idx = blockIdx.x * 256 + threadIdx.x;
    if (idx >= 27 * 64 * 64) return;
    int c = idx & 63, o = (idx >> 6) & 63, s = idx >> 12;
    int i = s / 9, t = s - i * 9;
    const float* wf = Wfuse + o * 192 + i * 64;
    const float* wd = Wd + ((size_t)(i * 64) * 64 + c) * 9 + t;
    float acc = 0.f;
    for (int c2 = 0; c2 < 64; ++c2)
        acc = fmaf(wf[c2], wd[(size_t)c2 * 576], acc);
    WcombB[idx] = f2bf(acc);   // idx == (s*64+o)*64 + c
}

// WoffR[t][n(64 pad)][c] bf16 from Woff[n][c][t], zero pad n>=54
__global__ void woffr_kernel(const float* __restrict__ Woff, unsigned short* __restrict__ WoffR) {
    int idx = blockIdx.x * 256 + threadIdx.x;
    if (idx >= 9 * 64 * 64) return;
    int c = idx & 63, n = (idx >> 6) & 63, t = idx >> 12;
    float v = (n < 54) ? Woff[(size_t)(n * 64 + c) * 9 + t] : 0.f;
    WoffR[idx] = f2bf(v);      // idx == (t*64+n)*64 + c
}

// Block = 4 waves, one 64-pixel row segment. Phase 1: offset conv as MFMA
// (B-frags direct from xT global). Phase 2: per-(i,t) slice, all 256 threads
// gather bilinear S[64c][64p] bf16 into LDS (double-buffered), 4 waves
// consume via 16x16x32 bf16 MFMA, M-split over out channels.
__launch_bounds__(256, 4)
__global__ void mspadc_main(const unsigned short* __restrict__ xT,
                            const unsigned short* __restrict__ WoffR,
                            const float* __restrict__ boff,
                            const unsigned short* __restrict__ WcombB,
                            float* __restrict__ out) {
    __shared__ float offL[64 * 65];                       // [n][p] pitch 65
    __shared__ __align__(16) unsigned short Sb[2][64 * 72]; // [p][c] pitch 72

    const int tid = threadIdx.x, lane = tid & 63, wv = tid >> 6;
    const int l15 = lane & 15, lq = lane >> 4;

    const unsigned u = blockIdx.x;
    const int xcd = u & 7, v = u >> 3;                    // XCD-band swizzle
    const int row = xcd * 64 + (v >> 2);                  // 0..511
    const int b = row >> 8, h = row & 255;
    const int w0 = (v & 3) << 6;

    const unsigned short* xTb = xT + (size_t)b * HW * 64;

    f32x4 acc[4];
#pragma unroll
    for (int nt = 0; nt < 4; ++nt) acc[nt] = (f32x4){0.f, 0.f, 0.f, 0.f};

    // ---------------- Phase 1: offset conv GEMM ----------------
#pragma unroll
    for (int t = 0; t < 9; ++t) {
        const int hh = h + t / 3 - 1;
        const bool hv = (hh >= 0) && (hh < HH);
#pragma unroll
        for (int kk = 0; kk < 2; ++kk) {
            bf16x8 a = *(const bf16x8*)(WoffR + (size_t)((t * 64 + 16 * wv + l15) * 64 + kk * 32 + lq * 8));
#pragma unroll
            for (int nt = 0; nt < 4; ++nt) {
                const int ww = w0 + nt * 16 + l15 + (t % 3) - 1;
                bf16x8 bf_ = {0, 0, 0, 0, 0, 0, 0, 0};
                if (hv && ww >= 0 && ww < WW)
                    bf_ = *(const bf16x8*)(xTb + (size_t)(hh * WW + ww) * 64 + kk * 32 + lq * 8);
                acc[nt] = __builtin_amdgcn_mfma_f32_16x16x32_bf16(a, bf_, acc[nt], 0, 0, 0);
            }
        }
    }
    // D: row(off-chan) = 16wv + lq*4 + r, col(pixel) = nt*16 + l15
#pragma unroll
    for (int r = 0; r < 4; ++r) {
        const int nch = 16 * wv + lq * 4 + r;
        const float bo = (nch < 54) ? boff[nch] : 0.f;
#pragma unroll
        for (int nt = 0; nt < 4; ++nt)
            offL[nch * 65 + nt * 16 + l15] = acc[nt][r] + bo;
    }
    __syncthreads();

#pragma unroll
    for (int nt = 0; nt < 4; ++nt) acc[nt] = (f32x4){0.f, 0.f, 0.f, 0.f};

    // ---------------- Phase 2: gather + main GEMM ----------------
    auto produce = [&](int s, int buf) {
        const int i = s / 9, t = s - i * 9;
        const int d = 1 << i;
        const float dy = offL[(i * 18 + 2 * t) * 65 + lane];
        const float dx = offL[(i * 18 + 2 * t + 1) * 65 + lane];
        const float ys = (float)(h + (t / 3 - 1) * d) + dy;
        const float xs = (float)(w0 + lane + (t % 3 - 1) * d) + dx;
        const float y0f = floorf(ys), x0f = floorf(xs);
        const float wy1 = ys - y0f, wx1 = xs - x0f;
        const float wy0 = 1.f - wy1, wx0 = 1.f - wx1;
        const float vy0 = (y0f >= 0.f && y0f <= 255.f) ? 1.f : 0.f;
        const float vy1 = (y0f >= -1.f && y0f <= 254.f) ? 1.f : 0.f;
        const float vx0 = (x0f >= 0.f && x0f <= 255.f) ? 1.f : 0.f;
        const float vx1 = (x0f >= -1.f && x0f <= 254.f) ? 1.f : 0.f;
        const float c00 = wy0 * wx0 * vy0 * vx0;
        const float c01 = wy0 * wx1 * vy0 * vx1;
        const float c10 = wy1 * wx0 * vy1 * vx0;
        const float c11 = wy1 * wx1 * vy1 * vx1;
        const int y0 = (int)fminf(fmaxf(y0f, 0.f), 255.f);
        const int x0 = (int)fminf(fmaxf(x0f, 0.f), 255.f);
        const int oxs = (((int)fminf(fmaxf(x0f + 1.f, 0.f), 255.f)) - x0) * 64;
        const int oyW = (((int)fminf(fmaxf(y0f + 1.f, 0.f), 255.f)) - y0) * WW * 64;
        const unsigned short* base = xTb + (size_t)(y0 * WW + x0) * 64 + wv * 16;
#pragma unroll
        for (int ch = 0; ch < 2; ++ch) {
            const unsigned short* pc = base + ch * 8;
            const uint4 u00 = *(const uint4*)(pc);
            const uint4 u01 = *(const uint4*)(pc + oxs);
            const uint4 u10 = *(const uint4*)(pc + oyW);
            const uint4 u11 = *(const uint4*)(pc + oyW + oxs);
            const unsigned a00[4] = {u00.x, u00.y, u00.z, u00.w};
            const unsigned a01[4] = {u01.x, u01.y, u01.z, u01.w};
            const unsigned a10[4] = {u10.x, u10.y, u10.z, u10.w};
            const unsigned a11[4] = {u11.x, u11.y, u11.z, u11.w};
            unsigned q[4];
#pragma unroll
            for (int j = 0; j < 4; ++j) {
                float lo = c00 * blo(a00[j]);
                lo = fmaf(c01, blo(a01[j]), lo);
                lo = fmaf(c10, blo(a10[j]), lo);
                lo = fmaf(c11, blo(a11[j]), lo);
                float hi = c00 * bhi(a00[j]);
                hi = fmaf(c01, bhi(a01[j]), hi);
                hi = fmaf(c10, bhi(a10[j]), hi);
                hi = fmaf(c11, bhi(a11[j]), hi);
                q[j] = (unsigned)f2bf(lo) | ((unsigned)f2bf(hi) << 16);
            }
            *(uint4*)(&Sb[buf][lane * 72 + wv * 16 + ch * 8]) = make_uint4(q[0], q[1], q[2], q[3]);
        }
    };

    auto consume = [&](int s, int buf) {
#pragma unroll
        for (int kk = 0; kk < 2; ++kk) {
            bf16x8 a = *(const bf16x8*)(WcombB + (size_t)((s * 64 + 16 * wv + l15) * 64 + kk * 32 + lq * 8));
#pragma unroll
            for (int nt = 0; nt < 4; ++nt) {
                bf16x8 bb = *(const bf16x8*)(&Sb[buf][(nt * 16 + l15) * 72 + kk * 32 + lq * 8]);
                acc[nt] = __builtin_amdgcn_mfma_f32_16x16x32_bf16(a, bb, acc[nt], 0, 0, 0);
            }
        }
    };

    produce(0, 0);
    __syncthreads();
    for (int s = 0; s < 27; ++s) {
        if (s < 26) produce(s + 1, (s + 1) & 1);
        consume(s, s & 1);
        __syncthreads();
    }

    // ---------------- Epilogue ----------------
    float* ob = out + (size_t)b * 64 * HW + h * WW + w0;
#pragma unroll
    for (int nt = 0; nt < 4; ++nt)
#pragma unroll
        for (int r = 0; r < 4; ++r) {
            const int o = 16 * wv + lq * 4 + r;
            ob[(size_t)o * HW + nt * 16 + l15] = acc[nt][r];
        }
}

extern "C" void kernel_launch(void* const* d_in, const int* in_sizes, int n_in,
                              void* d_out, int out_size, void* d_ws, size_t ws_size,
                              hipStream_t stream) {
    const float* x     = (const float*)d_in[0];
    const float* Woff  = (const float*)d_in[1];
    const float* boff  = (const float*)d_in[2];
    const float* Wd    = (const float*)d_in[3];
    const float* Wfuse = (const float*)d_in[4];
    float* out = (float*)d_out;

    unsigned short* WcombB = (unsigned short*)d_ws;        // 27*64*64*2   = 221184 B
    unsigned short* WoffR  = WcombB + 27 * 64 * 64;        // 9*64*64*2    =  73728 B
    unsigned short* xT     = WoffR + 9 * 64 * 64;          // 2*HW*64*2    = 16.78 MB

    xt_kernel<<<512, 256, 0, stream>>>(x, xT);
    wcomb_kernel<<<432, 256, 0, stream>>>(Wd, Wfuse, WcombB);
    woffr_kernel<<<144, 256, 0, stream>>>(Woff, WoffR);
    mspadc_main<<<2048, 256, 0, stream>>>(xT, WoffR, boff, WcombB, out);
}

// Round 5
// 302.020 us; speedup vs baseline: 8.9295x; 1.3696x over previous
//
#include <hip/hip_runtime.h>

#define HH 256
#define WW 256
#define HW (HH * WW)

typedef float f32x4 __attribute__((ext_vector_type(4)));
typedef short bf16x8 __attribute__((ext_vector_type(8)));

__device__ __forceinline__ unsigned short f2bf(float f) {
    unsigned u = __builtin_bit_cast(unsigned, f);
    return (unsigned short)((u + 0x7FFFu + ((u >> 16) & 1u)) >> 16);
}
__device__ __forceinline__ float blo(unsigned u) { return __builtin_bit_cast(float, u << 16); }
__device__ __forceinline__ float bhi(unsigned u) { return __builtin_bit_cast(float, u & 0xFFFF0000u); }

// x[b][c][h][w] fp32 -> xT[b][h][w][c] bf16  (channel-last for contiguous-channel gathers)
__global__ void xt_kernel(const float* __restrict__ x, unsigned short* __restrict__ xT) {
    const int pix = blockIdx.x * 256 + threadIdx.x;       // 0..131071
    const float* xp = x + (size_t)(pix >> 16) * 64 * HW + (pix & 65535);
    unsigned short* op = xT + (size_t)pix * 64;
#pragma unroll
    for (int c8 = 0; c8 < 8; ++c8) {
        unsigned q[4];
#pragma unroll
        for (int j = 0; j < 4; ++j) {
            float a = xp[(size_t)(c8 * 8 + 2 * j) * HW];
            float b = xp[(size_t)(c8 * 8 + 2 * j + 1) * HW];
            q[j] = (unsigned)f2bf(a) | ((unsigned)f2bf(b) << 16);
        }
        *(uint4*)(op + c8 * 8) = make_uint4(q[0], q[1], q[2], q[3]);
    }
}

// Fused weight prep:
//  WcombB[s][o][c] bf16 (s=i*9+t): sum_c2 Wfuse[o][i*64+c2] * Wd[i][c2][c][t]
//  WoffR[t][n(64 pad)][c] bf16 from Woff[n][c][t]
__global__ void wprep_kernel(const float* __restrict__ Wd,
                             const float* __restrict__ Wfuse,
                             const float* __restrict__ Woff,
                             unsigned short* __restrict__ WcombB,
                             unsigned short* __restrict__ WoffR) {
    int idx = blockIdx.x * 256 + threadIdx.x;
    if (idx < 27 * 64 * 64) {
        int c = idx & 63, o = (idx >> 6) & 63, s = idx >> 12;
        int i = s / 9, t = s - i * 9;
        const float* wf = Wfuse + o * 192 + i * 64;
        const float* wd = Wd + ((size_t)(i * 64) * 64 + c) * 9 + t;
        float acc = 0.f;
        for (int c2 = 0; c2 < 64; ++c2)
            acc = fmaf(wf[c2], wd[(size_t)c2 * 576], acc);
        WcombB[idx] = f2bf(acc);
    } else {
        int j = idx - 27 * 64 * 64;
        if (j < 9 * 64 * 64) {
            int c = j & 63, n = (j >> 6) & 63, t = j >> 12;
            float v = (n < 54) ? Woff[(size_t)(n * 64 + c) * 9 + t] : 0.f;
            WoffR[j] = f2bf(v);
        }
    }
}

// Block = 4 waves, one 64-pixel row segment. Phase 1: offset conv as MFMA.
// Phase 2: per-(i,t) slice, 256 threads gather bilinear S[64p][64c] bf16 into
// LDS with lane = (pixel, ch-chunk) so 8 lanes cover one 128B line (8 lines
// per VMEM instr instead of 64); 4 waves consume via 16x16x32 bf16 MFMA.
__launch_bounds__(256, 4)
__global__ void mspadc_main(const unsigned short* __restrict__ xT,
                            const unsigned short* __restrict__ WoffR,
                            const float* __restrict__ boff,
                            const unsigned short* __restrict__ WcombB,
                            float* __restrict__ out) {
    __shared__ float offL[64 * 65];                          // [n][p] pitch 65
    __shared__ __align__(16) unsigned short Sb[2][64 * 66];  // [p][c] pitch 66 (33 dw, odd)

    const int tid = threadIdx.x, lane = tid & 63, wv = tid >> 6;
    const int l15 = lane & 15, lq = lane >> 4;

    const unsigned u = blockIdx.x;
    const int xcd = u & 7, v = u >> 3;                    // XCD-band swizzle
    const int row = xcd * 64 + (v >> 2);                  // 0..511
    const int b = row >> 8, h = row & 255;
    const int w0 = (v & 3) << 6;

    const unsigned short* xTb = xT + (size_t)b * HW * 64;

    f32x4 acc[4];
#pragma unroll
    for (int nt = 0; nt < 4; ++nt) acc[nt] = (f32x4){0.f, 0.f, 0.f, 0.f};

    // ---------------- Phase 1: offset conv GEMM ----------------
#pragma unroll
    for (int t = 0; t < 9; ++t) {
        const int hh = h + t / 3 - 1;
        const bool hv = (hh >= 0) && (hh < HH);
#pragma unroll
        for (int kk = 0; kk < 2; ++kk) {
            bf16x8 a = *(const bf16x8*)(WoffR + (size_t)((t * 64 + 16 * wv + l15) * 64 + kk * 32 + lq * 8));
#pragma unroll
            for (int nt = 0; nt < 4; ++nt) {
                const int ww = w0 + nt * 16 + l15 + (t % 3) - 1;
                bf16x8 bf_ = {0, 0, 0, 0, 0, 0, 0, 0};
                if (hv && ww >= 0 && ww < WW)
                    bf_ = *(const bf16x8*)(xTb + (size_t)(hh * WW + ww) * 64 + kk * 32 + lq * 8);
                acc[nt] = __builtin_amdgcn_mfma_f32_16x16x32_bf16(a, bf_, acc[nt], 0, 0, 0);
            }
        }
    }
    // D: row(off-chan) = 16wv + lq*4 + r, col(pixel) = nt*16 + l15
#pragma unroll
    for (int r = 0; r < 4; ++r) {
        const int nch = 16 * wv + lq * 4 + r;
        const float bo = (nch < 54) ? boff[nch] : 0.f;
#pragma unroll
        for (int nt = 0; nt < 4; ++nt)
            offL[nch * 65 + nt * 16 + l15] = acc[nt][r] + bo;
    }
    __syncthreads();

#pragma unroll
    for (int nt = 0; nt < 4; ++nt) acc[nt] = (f32x4){0.f, 0.f, 0.f, 0.f};

    // ---------------- Phase 2: gather + main GEMM ----------------
    const int c8 = tid & 7;        // channel chunk (8 ch = 16B)
    const int psub = tid >> 3;     // pixel 0..31 (+32 on second pass)

    auto produce = [&](int s, int buf) {
        const int i = s / 9, t = s - i * 9;
        const int d = 1 << i;
#pragma unroll
        for (int r8 = 0; r8 < 2; ++r8) {
            const int p = 32 * r8 + psub;
            const float dy = offL[(i * 18 + 2 * t) * 65 + p];
            const float dx = offL[(i * 18 + 2 * t + 1) * 65 + p];
            const float ys = (float)(h + (t / 3 - 1) * d) + dy;
            const float xs = (float)(w0 + p + (t % 3 - 1) * d) + dx;
            const float y0f = floorf(ys), x0f = floorf(xs);
            const float wy1 = ys - y0f, wx1 = xs - x0f;
            const float wy0 = 1.f - wy1, wx0 = 1.f - wx1;
            const float vy0 = (y0f >= 0.f && y0f <= 255.f) ? 1.f : 0.f;
            const float vy1 = (y0f >= -1.f && y0f <= 254.f) ? 1.f : 0.f;
            const float vx0 = (x0f >= 0.f && x0f <= 255.f) ? 1.f : 0.f;
            const float vx1 = (x0f >= -1.f && x0f <= 254.f) ? 1.f : 0.f;
            const float c00 = wy0 * wx0 * vy0 * vx0;
            const float c01 = wy0 * wx1 * vy0 * vx1;
            const float c10 = wy1 * wx0 * vy1 * vx0;
            const float c11 = wy1 * wx1 * vy1 * vx1;
            const int y0 = (int)fminf(fmaxf(y0f, 0.f), 255.f);
            const int x0 = (int)fminf(fmaxf(x0f, 0.f), 255.f);
            const int oxs = (((int)fminf(fmaxf(x0f + 1.f, 0.f), 255.f)) - x0) * 64;
            const int oyW = (((int)fminf(fmaxf(y0f + 1.f, 0.f), 255.f)) - y0) * WW * 64;
            const unsigned short* pc = xTb + (size_t)(y0 * WW + x0) * 64 + c8 * 8;
            const uint4 u00 = *(const uint4*)(pc);
            const uint4 u01 = *(const uint4*)(pc + oxs);
            const uint4 u10 = *(const uint4*)(pc + oyW);
            const uint4 u11 = *(const uint4*)(pc + oyW + oxs);
            const unsigned a00[4] = {u00.x, u00.y, u00.z, u00.w};
            const unsigned a01[4] = {u01.x, u01.y, u01.z, u01.w};
            const unsigned a10[4] = {u10.x, u10.y, u10.z, u10.w};
            const unsigned a11[4] = {u11.x, u11.y, u11.z, u11.w};
            unsigned q[4];
#pragma unroll
            for (int j = 0; j < 4; ++j) {
                float lo = c00 * blo(a00[j]);
                lo = fmaf(c01, blo(a01[j]), lo);
                lo = fmaf(c10, blo(a10[j]), lo);
                lo = fmaf(c11, blo(a11[j]), lo);
                float hi = c00 * bhi(a00[j]);
                hi = fmaf(c01, bhi(a01[j]), hi);
                hi = fmaf(c10, bhi(a10[j]), hi);
                hi = fmaf(c11, bhi(a11[j]), hi);
                q[j] = (unsigned)f2bf(lo) | ((unsigned)f2bf(hi) << 16);
            }
            *(uint4*)(&Sb[buf][p * 66 + c8 * 8]) = make_uint4(q[0], q[1], q[2], q[3]);
        }
    };

    auto consume = [&](int s, int buf) {
#pragma unroll
        for (int kk = 0; kk < 2; ++kk) {
            bf16x8 a = *(const bf16x8*)(WcombB + (size_t)((s * 64 + 16 * wv + l15) * 64 + kk * 32 + lq * 8));
#pragma unroll
            for (int nt = 0; nt < 4; ++nt) {
                bf16x8 bb = *(const bf16x8*)(&Sb[buf][(nt * 16 + l15) * 66 + kk * 32 + lq * 8]);
                acc[nt] = __builtin_amdgcn_mfma_f32_16x16x32_bf16(a, bb, acc[nt], 0, 0, 0);
            }
        }
    };

    produce(0, 0);
    __syncthreads();
    for (int s = 0; s < 27; ++s) {
        if (s < 26) produce(s + 1, (s + 1) & 1);
        consume(s, s & 1);
        __syncthreads();
    }

    // ---------------- Epilogue ----------------
    float* ob = out + (size_t)b * 64 * HW + h * WW + w0;
#pragma unroll
    for (int nt = 0; nt < 4; ++nt)
#pragma unroll
        for (int r = 0; r < 4; ++r) {
            const int o = 16 * wv + lq * 4 + r;
            ob[(size_t)o * HW + nt * 16 + l15] = acc[nt][r];
        }
}

extern "C" void kernel_launch(void* const* d_in, const int* in_sizes, int n_in,
                              void* d_out, int out_size, void* d_ws, size_t ws_size,
                              hipStream_t stream) {
    const float* x     = (const float*)d_in[0];
    const float* Woff  = (const float*)d_in[1];
    const float* boff  = (const float*)d_in[2];
    const float* Wd    = (const float*)d_in[3];
    const float* Wfuse = (const float*)d_in[4];
    float* out = (float*)d_out;

    unsigned short* WcombB = (unsigned short*)d_ws;        // 27*64*64*2   = 221184 B
    unsigned short* WoffR  = WcombB + 27 * 64 * 64;        // 9*64*64*2    =  73728 B
    unsigned short* xT     = WoffR + 9 * 64 * 64;          // 2*HW*64*2    = 16.78 MB

    xt_kernel<<<512, 256, 0, stream>>>(x, xT);
    wprep_kernel<<<576, 256, 0, stream>>>(Wd, Wfuse, Woff, WcombB, WoffR);
    mspadc_main<<<2048, 256, 0, stream>>>(xT, WoffR, boff, WcombB, out);
}

// Round 9
// 300.813 us; speedup vs baseline: 8.9653x; 1.0040x over previous
//
#include <hip/hip_runtime.h>

#define HH 256
#define WW 256
#define HW (HH * WW)

typedef float f32x4 __attribute__((ext_vector_type(4)));
typedef float v2f __attribute__((ext_vector_type(2)));
typedef short bf16x8 __attribute__((ext_vector_type(8)));

__device__ __forceinline__ unsigned short f2bf(float f) {
    unsigned u = __builtin_bit_cast(unsigned, f);
    return (unsigned short)((u + 0x7FFFu + ((u >> 16) & 1u)) >> 16);
}
__device__ __forceinline__ v2f bfpair(unsigned u) {
    return (v2f){ __builtin_bit_cast(float, u << 16),
                  __builtin_bit_cast(float, u & 0xFFFF0000u) };
}

// x[b][c][h][w] fp32 -> xT[b][h][w][c] bf16  (channel-last for contiguous-channel gathers)
__global__ void xt_kernel(const float* __restrict__ x, unsigned short* __restrict__ xT) {
    const int pix = blockIdx.x * 256 + threadIdx.x;       // 0..131071
    const float* xp = x + (size_t)(pix >> 16) * 64 * HW + (pix & 65535);
    unsigned short* op = xT + (size_t)pix * 64;
#pragma unroll
    for (int c8 = 0; c8 < 8; ++c8) {
        unsigned q[4];
#pragma unroll
        for (int j = 0; j < 4; ++j) {
            float a = xp[(size_t)(c8 * 8 + 2 * j) * HW];
            float b = xp[(size_t)(c8 * 8 + 2 * j + 1) * HW];
            q[j] = (unsigned)f2bf(a) | ((unsigned)f2bf(b) << 16);
        }
        *(uint4*)(op + c8 * 8) = make_uint4(q[0], q[1], q[2], q[3]);
    }
}

// Weight prep:
//  WcombB[s][o][c] bf16 (s=i*9+t): sum_c2 Wfuse[o][i*64+c2] * Wd[i][c2][c][t]
//  WoffR[t][n(64 pad)][c] bf16 from Woff[n][c][t]
__global__ void wprep_kernel(const float* __restrict__ Wd,
                             const float* __restrict__ Wfuse,
                             const float* __restrict__ Woff,
                             unsigned short* __restrict__ WcombB,
                             unsigned short* __restrict__ WoffR) {
    int idx = blockIdx.x * 256 + threadIdx.x;
    if (idx < 27 * 64 * 64) {
        int c = idx & 63, o = (idx >> 6) & 63, s = idx >> 12;
        int i = s / 9, t = s - i * 9;
        const float* wf = Wfuse + o * 192 + i * 64;
        const float* wd = Wd + ((size_t)(i * 64) * 64 + c) * 9 + t;
        float acc = 0.f;
        for (int c2 = 0; c2 < 64; ++c2)
            acc = fmaf(wf[c2], wd[(size_t)c2 * 576], acc);
        WcombB[idx] = f2bf(acc);          // (s*64+o)*64 + c
    } else {
        int j = idx - 27 * 64 * 64;
        if (j < 9 * 64 * 64) {
            int c = j & 63, n = (j >> 6) & 63, t = j >> 12;
            float v = (n < 54) ? Woff[(size_t)(n * 64 + c) * 9 + t] : 0.f;
            WoffR[j] = f2bf(v);           // (t*64+n)*64 + c
        }
    }
}

// Block = 4 waves, one 64-pixel row segment. Exact R5 structure (known-good
// 302us baseline). SINGLE delta vs R5: the bilinear combine uses packed v2f
// FMAs (lo/hi channel in one op) — pack remains the exact-RNE f2bf, Sb pitch
// remains 66, produce/consume remain inline, prep remains two kernels.
__launch_bounds__(256, 4)
__global__ void mspadc_main(const unsigned short* __restrict__ xT,
                            const unsigned short* __restrict__ WoffR,
                            const float* __restrict__ boff,
                            const unsigned short* __restrict__ WcombB,
                            float* __restrict__ out) {
    __shared__ float offL[64 * 65];                          // [n][p] pitch 65
    __shared__ __align__(16) unsigned short Sb[2][64 * 66];  // [p][c] pitch 66

    const int tid = threadIdx.x, lane = tid & 63, wv = tid >> 6;
    const int l15 = lane & 15, lq = lane >> 4;

    const unsigned u = blockIdx.x;
    const int xcd = u & 7, v = u >> 3;                    // XCD-band swizzle
    const int row = xcd * 64 + (v >> 2);                  // 0..511
    const int b = row >> 8, h = row & 255;
    const int w0 = (v & 3) << 6;

    const unsigned short* xTb = xT + (size_t)b * HW * 64;

    f32x4 acc[4];
#pragma unroll
    for (int nt = 0; nt < 4; ++nt) acc[nt] = (f32x4){0.f, 0.f, 0.f, 0.f};

    // ---------------- Phase 1: offset conv GEMM ----------------
#pragma unroll
    for (int t = 0; t < 9; ++t) {
        const int hh = h + t / 3 - 1;
        const bool hv = (hh >= 0) && (hh < HH);
#pragma unroll
        for (int kk = 0; kk < 2; ++kk) {
            bf16x8 a = *(const bf16x8*)(WoffR + (size_t)((t * 64 + 16 * wv + l15) * 64 + kk * 32 + lq * 8));
#pragma unroll
            for (int nt = 0; nt < 4; ++nt) {
                const int ww = w0 + nt * 16 + l15 + (t % 3) - 1;
                bf16x8 bf_ = {0, 0, 0, 0, 0, 0, 0, 0};
                if (hv && ww >= 0 && ww < WW)
                    bf_ = *(const bf16x8*)(xTb + (size_t)(hh * WW + ww) * 64 + kk * 32 + lq * 8);
                acc[nt] = __builtin_amdgcn_mfma_f32_16x16x32_bf16(a, bf_, acc[nt], 0, 0, 0);
            }
        }
    }
#pragma unroll
    for (int r = 0; r < 4; ++r) {
        const int nch = 16 * wv + lq * 4 + r;
        const float bo = (nch < 54) ? boff[nch] : 0.f;
#pragma unroll
        for (int nt = 0; nt < 4; ++nt)
            offL[nch * 65 + nt * 16 + l15] = acc[nt][r] + bo;
    }
    __syncthreads();

#pragma unroll
    for (int nt = 0; nt < 4; ++nt) acc[nt] = (f32x4){0.f, 0.f, 0.f, 0.f};

    // ---------------- Phase 2: gather + main GEMM ----------------
    const int c8 = tid & 7;        // channel chunk (8 ch = 16B)
    const int psub = tid >> 3;     // pixel 0..31 (+32 second half)

    auto produce = [&](int s, int buf) {
        const int i = s / 9, t = s - i * 9;
        const int d = 1 << i;
#pragma unroll
        for (int r8 = 0; r8 < 2; ++r8) {
            const int p = 32 * r8 + psub;
            const float dy = offL[(i * 18 + 2 * t) * 65 + p];
            const float dx = offL[(i * 18 + 2 * t + 1) * 65 + p];
            const float ys = (float)(h + (t / 3 - 1) * d) + dy;
            const float xs = (float)(w0 + p + (t % 3 - 1) * d) + dx;
            const float y0f = floorf(ys), x0f = floorf(xs);
            const float wy1 = ys - y0f, wx1 = xs - x0f;
            const float wy0 = 1.f - wy1, wx0 = 1.f - wx1;
            const float vy0 = (y0f >= 0.f && y0f <= 255.f) ? 1.f : 0.f;
            const float vy1 = (y0f >= -1.f && y0f <= 254.f) ? 1.f : 0.f;
            const float vx0 = (x0f >= 0.f && x0f <= 255.f) ? 1.f : 0.f;
            const float vx1 = (x0f >= -1.f && x0f <= 254.f) ? 1.f : 0.f;
            const float c00 = wy0 * wx0 * vy0 * vx0;
            const float c01 = wy0 * wx1 * vy0 * vx1;
            const float c10 = wy1 * wx0 * vy1 * vx0;
            const float c11 = wy1 * wx1 * vy1 * vx1;
            const int y0 = (int)fminf(fmaxf(y0f, 0.f), 255.f);
            const int x0 = (int)fminf(fmaxf(x0f, 0.f), 255.f);
            const int oxs = (((int)fminf(fmaxf(x0f + 1.f, 0.f), 255.f)) - x0) * 64;
            const int oyW = (((int)fminf(fmaxf(y0f + 1.f, 0.f), 255.f)) - y0) * WW * 64;
            const unsigned short* pc = xTb + (size_t)(y0 * WW + x0) * 64 + c8 * 8;
            const uint4 u00 = *(const uint4*)(pc);
            const uint4 u01 = *(const uint4*)(pc + oxs);
            const uint4 u10 = *(const uint4*)(pc + oyW);
            const uint4 u11 = *(const uint4*)(pc + oyW + oxs);
            const unsigned a00[4] = {u00.x, u00.y, u00.z, u00.w};
            const unsigned a01[4] = {u01.x, u01.y, u01.z, u01.w};
            const unsigned a10[4] = {u10.x, u10.y, u10.z, u10.w};
            const unsigned a11[4] = {u11.x, u11.y, u11.z, u11.w};
            const v2f c00v = {c00, c00}, c01v = {c01, c01};
            const v2f c10v = {c10, c10}, c11v = {c11, c11};
            unsigned q[4];
#pragma unroll
            for (int j = 0; j < 4; ++j) {
                v2f s2 = bfpair(a00[j]) * c00v;
                s2 = __builtin_elementwise_fma(bfpair(a01[j]), c01v, s2);
                s2 = __builtin_elementwise_fma(bfpair(a10[j]), c10v, s2);
                s2 = __builtin_elementwise_fma(bfpair(a11[j]), c11v, s2);
                q[j] = (unsigned)f2bf(s2.x) | ((unsigned)f2bf(s2.y) << 16);
            }
            *(uint4*)(&Sb[buf][p * 66 + c8 * 8]) = make_uint4(q[0], q[1], q[2], q[3]);
        }
    };

    auto consume = [&](int s, int buf) {
#pragma unroll
        for (int kk = 0; kk < 2; ++kk) {
            bf16x8 a = *(const bf16x8*)(WcombB + (size_t)((s * 64 + 16 * wv + l15) * 64 + kk * 32 + lq * 8));
#pragma unroll
            for (int nt = 0; nt < 4; ++nt) {
                bf16x8 bb = *(const bf16x8*)(&Sb[buf][(nt * 16 + l15) * 66 + kk * 32 + lq * 8]);
                acc[nt] = __builtin_amdgcn_mfma_f32_16x16x32_bf16(a, bb, acc[nt], 0, 0, 0);
            }
        }
    };

    produce(0, 0);
    __syncthreads();
    for (int s = 0; s < 27; ++s) {
        if (s < 26) produce(s + 1, (s + 1) & 1);
        consume(s, s & 1);
        __syncthreads();
    }

    // ---------------- Epilogue ----------------
    float* ob = out + (size_t)b * 64 * HW + h * WW + w0;
#pragma unroll
    for (int nt = 0; nt < 4; ++nt)
#pragma unroll
        for (int r = 0; r < 4; ++r) {
            const int o = 16 * wv + lq * 4 + r;
            ob[(size_t)o * HW + nt * 16 + l15] = acc[nt][r];
        }
}

extern "C" void kernel_launch(void* const* d_in, const int* in_sizes, int n_in,
                              void* d_out, int out_size, void* d_ws, size_t ws_size,
                              hipStream_t stream) {
    const float* x     = (const float*)d_in[0];
    const float* Woff  = (const float*)d_in[1];
    const float* boff  = (const float*)d_in[2];
    const float* Wd    = (const float*)d_in[3];
    const float* Wfuse = (const float*)d_in[4];
    float* out = (float*)d_out;

    unsigned short* WcombB = (unsigned short*)d_ws;        // 27*64*64*2   = 221184 B
    unsigned short* WoffR  = WcombB + 27 * 64 * 64;        // 9*64*64*2    =  73728 B
    unsigned short* xT     = WoffR + 9 * 64 * 64;          // 2*HW*64*2    = 16.78 MB

    xt_kernel<<<512, 256, 0, stream>>>(x, xT);
    wprep_kernel<<<576, 256, 0, stream>>>(Wd, Wfuse, Woff, WcombB, WoffR);
    mspadc_main<<<2048, 256, 0, stream>>>(xT, WoffR, boff, WcombB, out);
}